// Round 1
// baseline (343.800 us; speedup 1.0000x reference)
//
#include <hip/hip_runtime.h>
#include <hip/hip_fp16.h>
#include <stdint.h>

#define BB 512
#define TT 1024
#define II 15
#define HH 64
#define OO 11

typedef __fp16 half2v __attribute__((ext_vector_type(2)));
typedef _Float16 half8 __attribute__((ext_vector_type(8)));
typedef float floatx4 __attribute__((ext_vector_type(4)));
typedef int int4v __attribute__((ext_vector_type(4)));

union PK { int i; half2v h; float f; };

__device__ __forceinline__ half2v i2h2(int v) { PK u; u.i = v; return u.h; }
__device__ __forceinline__ int h22i(half2v v) { PK u; u.h = v; return u.i; }

__device__ __forceinline__ float FDOT2(half2v a, half2v b, float c) {
    return __builtin_amdgcn_fdot2(a, b, c, false);
}

__device__ __forceinline__ float lane_xor1(float v) {
    PK u; u.f = v;
    // quad_perm(1,0,3,2) = 0xB1 : lane -> lane^1
    u.i = __builtin_amdgcn_mov_dpp(u.i, 0xB1, 0xF, 0xF, false);
    return u.f;
}

// One wave per batch, lane = h_out.
// v3: the h(t-1) broadcast is now ENTIRELY in-register: 32 x v_readlane of the
// packed pair register hpk (even lane 2q holds (h[2q],h[2q+1])), each feeding a
// v_dot2 with the SGPR as the h operand (1 SGPR read per VALU op = legal).
// This removes the per-step LDS round trip (ds_write h -> 6 uniform
// ds_read_b128 -> lgkmcnt drain) that was the dominant exposed latency at
// 0.5 waves/SIMD. Remaining DS traffic: only the 2 x-pair reads per step,
// issued at step top (independent of h, latency fully hidden).
// xproj(t+1) computed during step t (xa[8]); x double-buffered per 64 steps.
__global__ __launch_bounds__(64) void rnn_rec(
    const float* __restrict__ x, const float* __restrict__ W_ih,
    const float* __restrict__ b_ih, const float* __restrict__ W_hh,
    const float* __restrict__ b_hh, _Float16* __restrict__ hs,
    float* __restrict__ h_last)
{
    __shared__ __align__(16) int xbuf[2][64 * 8];  // [buf][step][8 packed pairs]
    const int b = blockIdx.x;
    const int lane = threadIdx.x;

    // recurrent weights: whh[p] = (W_hh[lane][2p], W_hh[lane][2p+1])
    half2v whh[32];
#pragma unroll
    for (int p = 0; p < 32; ++p)
        whh[p] = __builtin_amdgcn_cvt_pkrtz(W_hh[lane * HH + 2 * p],
                                            W_hh[lane * HH + 2 * p + 1]);
    // input weights; pair 7 = (w14, bias) matching x pair (x14, 1.0)
    half2v wx[8];
#pragma unroll
    for (int j = 0; j < 7; ++j)
        wx[j] = __builtin_amdgcn_cvt_pkrtz(W_ih[lane * II + 2 * j],
                                           W_ih[lane * II + 2 * j + 1]);
    wx[7] = __builtin_amdgcn_cvt_pkrtz(W_ih[lane * II + 14],
                                       b_ih[lane] + b_hh[lane]);

    const float* xb = x + (size_t)b * TT * II;
    _Float16* hrow = hs + (size_t)b * TT * HH + lane;

    // stage chunk 0 into xbuf[0]: lane ts packs x[b][ts][0..14] -> 8 pairs
    {
        float cf[II];
#pragma unroll
        for (int i = 0; i < II; ++i) cf[i] = xb[lane * II + i];
        int4v p0, p1;
        p0.x = h22i(__builtin_amdgcn_cvt_pkrtz(cf[0], cf[1]));
        p0.y = h22i(__builtin_amdgcn_cvt_pkrtz(cf[2], cf[3]));
        p0.z = h22i(__builtin_amdgcn_cvt_pkrtz(cf[4], cf[5]));
        p0.w = h22i(__builtin_amdgcn_cvt_pkrtz(cf[6], cf[7]));
        p1.x = h22i(__builtin_amdgcn_cvt_pkrtz(cf[8], cf[9]));
        p1.y = h22i(__builtin_amdgcn_cvt_pkrtz(cf[10], cf[11]));
        p1.z = h22i(__builtin_amdgcn_cvt_pkrtz(cf[12], cf[13]));
        p1.w = h22i(__builtin_amdgcn_cvt_pkrtz(cf[14], 1.0f));
        *(int4v*)&xbuf[0][lane * 8] = p0;
        *(int4v*)&xbuf[0][lane * 8 + 4] = p1;
    }

    // xproj accumulators for step 0 (read back slot 0; wave-synchronous)
    float xa[8];
    {
        const int4v xv0 = *(const int4v*)&xbuf[0][0];
        const int4v xv1 = *(const int4v*)&xbuf[0][4];
        xa[0] = FDOT2(i2h2(xv0.x), wx[0], 0.0f);
        xa[1] = FDOT2(i2h2(xv0.y), wx[1], 0.0f);
        xa[2] = FDOT2(i2h2(xv0.z), wx[2], 0.0f);
        xa[3] = FDOT2(i2h2(xv0.w), wx[3], 0.0f);
        xa[4] = FDOT2(i2h2(xv1.x), wx[4], 0.0f);
        xa[5] = FDOT2(i2h2(xv1.y), wx[5], 0.0f);
        xa[6] = FDOT2(i2h2(xv1.z), wx[6], 0.0f);
        xa[7] = FDOT2(i2h2(xv1.w), wx[7], 0.0f);
    }

    float h = 0.0f;
    int hpk = 0;   // packed (h[lane&~1], h[lane|1]) from previous step (h=0)

    auto step = [&](int t) {
        // x pairs for step t+1 — DS pipe is otherwise idle now; issue first
        // so their latency hides under the readlane/dot chain.
        const int tn = t + 1;
        const int* xp = &xbuf[(tn >> 6) & 1][(tn & 63) * 8];
        const int4v xv0 = *(const int4v*)xp;
        const int4v xv1 = *(const int4v*)(xp + 4);

        // seed with precomputed xproj
        float a[8];
#pragma unroll
        for (int j = 0; j < 8; ++j) a[j] = xa[j];

        // full in-register broadcast of h(t-1): pair q lives in lane 2q's hpk.
        // readlane is wave-synchronous VALU; dot consumes the SGPR directly.
        // acc index q&7 keeps each accumulator's dep chain 8 instrs apart.
#pragma unroll
        for (int q = 0; q < 32; ++q) {
            const int hq = __builtin_amdgcn_readlane(hpk, 2 * q);
            a[q & 7] = FDOT2(i2h2(hq), whh[q], a[q & 7]);
        }

        h = fmaxf(((a[0] + a[1]) + (a[2] + a[3])) +
                  ((a[4] + a[5]) + (a[6] + a[7])), 0.0f);
        const _Float16 hf = (_Float16)h;

        hrow[(size_t)t * HH] = hf;             // 128B contiguous global store

        // pack pair for next step's readlane broadcast (pure VALU)
        hpk = h22i(__builtin_amdgcn_cvt_pkrtz(h, lane_xor1(h)));

        // xproj for t+1 (consumes xv late; fills residual stall)
        xa[0] = FDOT2(i2h2(xv0.x), wx[0], 0.0f);
        xa[1] = FDOT2(i2h2(xv0.y), wx[1], 0.0f);
        xa[2] = FDOT2(i2h2(xv0.z), wx[2], 0.0f);
        xa[3] = FDOT2(i2h2(xv0.w), wx[3], 0.0f);
        xa[4] = FDOT2(i2h2(xv1.x), wx[4], 0.0f);
        xa[5] = FDOT2(i2h2(xv1.y), wx[5], 0.0f);
        xa[6] = FDOT2(i2h2(xv1.z), wx[6], 0.0f);
        xa[7] = FDOT2(i2h2(xv1.w), wx[7], 0.0f);
    };

    for (int tc = 0; tc < TT; tc += 64) {
        // global prefetch of the next chunk (re-reads current on the last one)
        const int tnb = (tc + 64 < TT) ? (tc + 64) : tc;
        float nf[II];
#pragma unroll
        for (int i = 0; i < II; ++i)
            nf[i] = xb[(size_t)(tnb + lane) * II + i];

        for (int to = 0; to < 32; to += 8)
#pragma unroll
            for (int u = 0; u < 8; ++u) step(tc + to + u);

        // commit prefetched chunk into the other xbuf half (t+1 reads touch
        // it only from ts=63; committed here at ts=32)
        {
            const int cb = ((tc >> 6) + 1) & 1;
            int4v p0, p1;
            p0.x = h22i(__builtin_amdgcn_cvt_pkrtz(nf[0], nf[1]));
            p0.y = h22i(__builtin_amdgcn_cvt_pkrtz(nf[2], nf[3]));
            p0.z = h22i(__builtin_amdgcn_cvt_pkrtz(nf[4], nf[5]));
            p0.w = h22i(__builtin_amdgcn_cvt_pkrtz(nf[6], nf[7]));
            p1.x = h22i(__builtin_amdgcn_cvt_pkrtz(nf[8], nf[9]));
            p1.y = h22i(__builtin_amdgcn_cvt_pkrtz(nf[10], nf[11]));
            p1.z = h22i(__builtin_amdgcn_cvt_pkrtz(nf[12], nf[13]));
            p1.w = h22i(__builtin_amdgcn_cvt_pkrtz(nf[14], 1.0f));
            *(int4v*)&xbuf[cb][lane * 8] = p0;
            *(int4v*)&xbuf[cb][lane * 8 + 4] = p1;
        }

        for (int to = 32; to < 64; to += 8)
#pragma unroll
            for (int u = 0; u < 8; ++u) step(tc + to + u);
    }
    h_last[b * HH + lane] = h;
}

// Decoder: one 16x16x64 tile per wave (16 consecutive (b,t) rows of one batch).
// hs read: 2KB contiguous per wave; out store: 704B contiguous per tile.
__global__ __launch_bounds__(256) void rnn_decode(
    const _Float16* __restrict__ hs, const float* __restrict__ W_dec,
    const float* __restrict__ b_dec, float* __restrict__ out)
{
    __shared__ __align__(16) _Float16 wl[16 * HH];
    const int tid = threadIdx.x;
    for (int i = tid; i < 16 * HH; i += 256)
        wl[i] = (_Float16)((i < OO * HH) ? W_dec[i] : 0.0f);
    __syncthreads();

    const int lane = tid & 63;
    const int wid  = tid >> 6;
    const int col  = lane & 15;
    const int quad = lane >> 4;
    const float bd = (col < OO) ? b_dec[col] : 0.0f;

    half8 bf0 = *(const half8*)&wl[col * HH + quad * 8];
    half8 bf1 = *(const half8*)&wl[col * HH + 32 + quad * 8];

    const size_t tile = (size_t)blockIdx.x * 4 + wid;   // 0..32767
    const size_t btb = tile * 16;
    const _Float16* ap = hs + (btb + (size_t)col) * HH + quad * 8;
    half8 a0 = *(const half8*)ap;
    half8 a1 = *(const half8*)(ap + 32);

    floatx4 acc = {0.0f, 0.0f, 0.0f, 0.0f};
    acc = __builtin_amdgcn_mfma_f32_16x16x32_f16(a0, bf0, acc, 0, 0, 0);
    acc = __builtin_amdgcn_mfma_f32_16x16x32_f16(a1, bf1, acc, 0, 0, 0);

    if (col < OO) {
#pragma unroll
        for (int r = 0; r < 4; ++r) {
            const size_t row = btb + (size_t)(quad * 4 + r);
            out[row * OO + col] = fmaxf(acc[r] + bd, 0.0f);
        }
    }
}

extern "C" void kernel_launch(void* const* d_in, const int* in_sizes, int n_in,
                              void* d_out, int out_size, void* d_ws, size_t ws_size,
                              hipStream_t stream) {
    const float* x     = (const float*)d_in[0];
    const float* W_ih  = (const float*)d_in[1];
    const float* b_ih  = (const float*)d_in[2];
    const float* W_hh  = (const float*)d_in[3];
    const float* b_hh  = (const float*)d_in[4];
    const float* W_dec = (const float*)d_in[5];
    const float* b_dec = (const float*)d_in[6];

    float* out    = (float*)d_out;
    float* h_last = out + (size_t)BB * TT * OO;   // second tuple output
    _Float16* hs  = (_Float16*)d_ws;              // [B][T][H] f16, 64 MiB

    rnn_rec<<<BB, 64, 0, stream>>>(x, W_ih, b_ih, W_hh, b_hh, hs, h_last);
    rnn_decode<<<8192, 256, 0, stream>>>(hs, W_dec, b_dec, out);
}